// Round 13
// baseline (20.482 us; speedup 1.0000x reference)
//
#include <hip/hip_runtime.h>

#define K_TOTAL 32768
#define R_TOTAL 128
#define A_DIM   16
#define KB      128      // k-points per block (2 per lane)
#define RPW     8        // rules per wave (16 waves x 8 = 128)
#define NBUCK   32       // power of 2 -> exact fp quantization

#define REC 84   // floats per rule record in LDS (336 B)
// per-rule LDS record layout (floats), pair p = dims {2p, 2p+1}:
//   [ 4p .. 4p+3 ]      Q0[p] = { IBA0, IBA1, C1_0, C1_1 }
//   [32+4p .. 32+4p+3]  Q1[p] = { NID0, NID1, C3_0, C3_1 }
//   [64..79]            rho[0..15] ; [80] bias ; [81..83] pad

typedef float v2f __attribute__((ext_vector_type(2)));

__device__ __forceinline__ float clamp01(float v) {
    return __builtin_amdgcn_fmed3f(v, 0.0f, 1.0f);
}

// one dim-pair, two k-instances; 2x ds_read_b128 delivers all 8 constants
__device__ __forceinline__ void memb_pair2(const float* rec, int p,
                                           const v2f* Xa, const v2f* Xb,
                                           v2f& Wa, v2f& Wb) {
    float4 q0 = *(const float4*)(rec + 4 * p);
    float4 q1 = *(const float4*)(rec + 32 + 4 * p);
    v2f iba = (v2f){q0.x, q0.y}, c1 = (v2f){q0.z, q0.w};
    v2f nid = (v2f){q1.x, q1.y}, c3 = (v2f){q1.z, q1.w};
    v2f ra = Xa[p] * iba + c1;
    v2f fa = Xa[p] * nid + c3;
    v2f rb = Xb[p] * iba + c1;
    v2f fb = Xb[p] * nid + c3;
    v2f Ma, Mb;
    Ma.x = clamp01(fminf(ra.x, fa.x));
    Ma.y = clamp01(fminf(ra.y, fa.y));
    Mb.x = clamp01(fminf(rb.x, fb.x));
    Mb.y = clamp01(fminf(rb.y, fb.y));
    Wa *= Ma;
    Wb *= Mb;
}

// Single fused kernel. 256 blocks x 1024 threads (16 waves). Block owns
// 128 k's (2 per lane); wave wv owns rules [wv*8, wv*8+8).
//   1. per-wave fold of own rule constants into LDS + block-wide {a,d}
//      interval table (same loads serve both).
//   2. block-parallel LUT: per (dim,bucket) a 128-bit mask of rules whose
//      [a,d] intersects the bucket. Quantization (int)(x*32) is EXACT
//      (power-of-2 scale), so no false negatives; false positives give
//      exact +0 contributions -> identical support to reference.
//   3. per-lane AND of 16 per-dim masks -> ~90% of (wave,rule) pairs skip
//      the entire 16-dim evaluation with one AND + __any per rule.
__global__ __launch_bounds__(1024, 1)
void fuzzy_fused(const float* __restrict__ input,
                 const float* __restrict__ abcd,
                 const float* __restrict__ rho,
                 float* __restrict__ out) {
    __shared__ __align__(16) float tab[R_TOTAL * REC];   // 43008 B
    __shared__ float2 mnmx[R_TOTAL * A_DIM];             // 16384 B
    __shared__ uint4  lut[A_DIM * NBUCK];                //  8192 B
    __shared__ float  nsh[16][KB];                       //  8192 B
    __shared__ float  dsh[16][KB];                       //  8192 B

    const int t     = threadIdx.x;
    const int lane  = t & 63;
    const int wv    = __builtin_amdgcn_readfirstlane(t >> 6);
    const int kbase = blockIdx.x * KB;
    float* wtab = tab + wv * RPW * REC;

    // -------- fold own-wave rules (and block-wide interval table) ----------
    #pragma unroll
    for (int i = 0; i < 2; ++i) {
        int e  = lane + 64 * i;                // 0..127 within this wave
        int ge = wv * 128 + e;                 // global (r,a) entry
        int rr = e >> 4, a = e & 15, p = a >> 1, sl = a & 1;
        float4 v = ((const float4*)abcd)[ge];
        float v0 = v.x, v1 = v.y, v2 = v.z, v3 = v.w, s;
        s = fminf(v0, v1); v1 = fmaxf(v0, v1); v0 = s;
        s = fminf(v2, v3); v3 = fmaxf(v2, v3); v2 = s;
        s = fminf(v0, v2); v2 = fmaxf(v0, v2); v0 = s;
        s = fminf(v1, v3); v3 = fmaxf(v1, v3); v1 = s;
        s = fminf(v1, v2); v2 = fmaxf(v1, v2); v1 = s;
        // v0<=v1<=v2<=v3
        float iba = __builtin_amdgcn_rcpf(v1 - v0);
        float idc = __builtin_amdgcn_rcpf(v3 - v2);
        float* q = wtab + rr * REC;
        q[4 * p + sl]          =  iba;
        q[4 * p + 2 + sl]      = -v0 * iba;
        q[32 + 4 * p + sl]     = -idc;
        q[32 + 4 * p + 2 + sl] =  v3 * idc;
        mnmx[ge] = make_float2(v0, v3);        // support interval [a, d]
    }
    #pragma unroll
    for (int i = 0; i < 3; ++i) {
        int f = lane + 64 * i;                 // own-wave rho, < 136
        if (f < RPW * (A_DIM + 1)) {
            int rr = f / (A_DIM + 1);
            int c  = f - rr * (A_DIM + 1);
            wtab[rr * REC + 64 + c] = rho[wv * RPW * (A_DIM + 1) + f];
        }
    }

    // per-lane coordinates for the two k-instances (overlap fold latency)
    v2f Xa[8], Xb[8];
    {
        const float4* xp = (const float4*)(input + (size_t)(kbase + lane) * A_DIM);
        float4 a0 = xp[0], a1 = xp[1], a2 = xp[2], a3 = xp[3];
        Xa[0] = (v2f){a0.x, a0.y}; Xa[1] = (v2f){a0.z, a0.w};
        Xa[2] = (v2f){a1.x, a1.y}; Xa[3] = (v2f){a1.z, a1.w};
        Xa[4] = (v2f){a2.x, a2.y}; Xa[5] = (v2f){a2.z, a2.w};
        Xa[6] = (v2f){a3.x, a3.y}; Xa[7] = (v2f){a3.z, a3.w};
        const float4* yp = (const float4*)(input + (size_t)(kbase + 64 + lane) * A_DIM);
        float4 b0 = yp[0], b1 = yp[1], b2 = yp[2], b3 = yp[3];
        Xb[0] = (v2f){b0.x, b0.y}; Xb[1] = (v2f){b0.z, b0.w};
        Xb[2] = (v2f){b1.x, b1.y}; Xb[3] = (v2f){b1.z, b1.w};
        Xb[4] = (v2f){b2.x, b2.y}; Xb[5] = (v2f){b2.z, b2.w};
        Xb[6] = (v2f){b3.x, b3.y}; Xb[7] = (v2f){b3.z, b3.w};
    }

    __syncthreads();                           // mnmx (and tab) complete

    // -------- block-parallel LUT build (waves 0-7) --------------------------
    if (t < A_DIM * NBUCK) {
        int a = t >> 5;                        // dim
        int b = t & (NBUCK - 1);               // bucket
        float lo = (float)b * 0.03125f;        // exact
        float hi = (float)(b + 1) * 0.03125f;  // exact
        unsigned m0 = 0, m1 = 0, m2 = 0, m3 = 0;
        #pragma unroll 4
        for (int r = 0; r < 32; ++r) {         // half-wave-broadcast LDS reads
            float2 c0 = mnmx[((r      ) << 4) + a];
            float2 c1 = mnmx[((r +  32) << 4) + a];
            float2 c2 = mnmx[((r +  64) << 4) + a];
            float2 c3 = mnmx[((r +  96) << 4) + a];
            unsigned bit = 1u << r;
            if (c0.x <= hi && c0.y >= lo) m0 |= bit;
            if (c1.x <= hi && c1.y >= lo) m1 |= bit;
            if (c2.x <= hi && c2.y >= lo) m2 |= bit;
            if (c3.x <= hi && c3.y >= lo) m3 |= bit;
        }
        lut[t] = make_uint4(m0, m1, m2, m3);
    }
    __syncthreads();                           // lut complete

    // -------- per-lane candidate masks (AND over 16 dims, both ksets) ------
    uint4 mA = make_uint4(~0u, ~0u, ~0u, ~0u);
    uint4 mB = make_uint4(~0u, ~0u, ~0u, ~0u);
    #pragma unroll
    for (int p = 0; p < 8; ++p) {
        int bA0 = min((int)(Xa[p].x * (float)NBUCK), NBUCK - 1);
        int bA1 = min((int)(Xa[p].y * (float)NBUCK), NBUCK - 1);
        int bB0 = min((int)(Xb[p].x * (float)NBUCK), NBUCK - 1);
        int bB1 = min((int)(Xb[p].y * (float)NBUCK), NBUCK - 1);
        uint4 vA0 = lut[(2 * p) * NBUCK + bA0];
        uint4 vA1 = lut[(2 * p + 1) * NBUCK + bA1];
        uint4 vB0 = lut[(2 * p) * NBUCK + bB0];
        uint4 vB1 = lut[(2 * p + 1) * NBUCK + bB1];
        mA.x &= vA0.x & vA1.x;  mA.y &= vA0.y & vA1.y;
        mA.z &= vA0.z & vA1.z;  mA.w &= vA0.w & vA1.w;
        mB.x &= vB0.x & vB1.x;  mB.y &= vB0.y & vB1.y;
        mB.z &= vB0.z & vB1.z;  mB.w &= vB0.w & vB1.w;
    }
    // this wave's 8 rules live in one 32-bit word: word = wv>>2, uniform
    const int wsel = wv >> 2;
    unsigned mwA = (wsel & 2) ? ((wsel & 1) ? mA.w : mA.z)
                              : ((wsel & 1) ? mA.y : mA.x);
    unsigned mwB = (wsel & 2) ? ((wsel & 1) ? mB.w : mB.z)
                              : ((wsel & 1) ? mB.y : mB.x);
    const unsigned mw = mwA | mwB;
    const int bitbase = (wv & 3) * 8;

    // -------- Phase 2: stream this wave's 8 rules (mostly skipped) ---------
    float numA = 0.0f, denA = 0.0f, numB = 0.0f, denB = 0.0f;

    #pragma unroll
    for (int rr = 0; rr < RPW; ++rr) {
        if (!__any((mw >> (bitbase + rr)) & 1u)) continue;   // ~90% skip

        const float* rec = wtab + rr * REC;

        v2f Wa = (v2f){1.0f, 1.0f}, Wb = (v2f){1.0f, 1.0f};
        memb_pair2(rec, 0, Xa, Xb, Wa, Wb);
        memb_pair2(rec, 1, Xa, Xb, Wa, Wb);
        memb_pair2(rec, 2, Xa, Xb, Wa, Wb);
        memb_pair2(rec, 3, Xa, Xb, Wa, Wb);
        float w8a = Wa.x * Wa.y, w8b = Wb.x * Wb.y;
        if (__any((w8a != 0.0f) | (w8b != 0.0f))) {
            memb_pair2(rec, 4, Xa, Xb, Wa, Wb);
            memb_pair2(rec, 5, Xa, Xb, Wa, Wb);
            float w12a = Wa.x * Wa.y, w12b = Wb.x * Wb.y;
            if (__any((w12a != 0.0f) | (w12b != 0.0f))) {
                memb_pair2(rec, 6, Xa, Xb, Wa, Wb);
                memb_pair2(rec, 7, Xa, Xb, Wa, Wb);
                float wfa = Wa.x * Wa.y, wfb = Wb.x * Wb.y;
                if (__any((wfa != 0.0f) | (wfb != 0.0f))) {
                    v2f accA = (v2f){rec[80], 0.0f};
                    v2f accB = (v2f){rec[80], 0.0f};
                    #pragma unroll
                    for (int p4 = 0; p4 < 4; ++p4) {
                        float4 rh = *(const float4*)(rec + 64 + 4 * p4);
                        v2f r0 = (v2f){rh.x, rh.y}, r1 = (v2f){rh.z, rh.w};
                        accA += Xa[2*p4] * r0;  accA += Xa[2*p4+1] * r1;
                        accB += Xb[2*p4] * r0;  accB += Xb[2*p4+1] * r1;
                    }
                    float za = accA.x + accA.y;
                    float zb = accB.x + accB.y;
                    numA = fmaf(za, wfa, numA);  denA += wfa;
                    numB = fmaf(zb, wfb, numB);  denB += wfb;
                }
            }
        }
    }

    // -------- Phase 3: reduce across the 16 waves --------------------------
    nsh[wv][lane]      = numA;
    dsh[wv][lane]      = denA;
    nsh[wv][64 + lane] = numB;
    dsh[wv][64 + lane] = denB;
    __syncthreads();

    if (t < KB) {
        float n = 0.0f, d = 0.0f;
        #pragma unroll
        for (int c = 0; c < 16; ++c) { n += nsh[c][t]; d += dsh[c][t]; }
        out[kbase + t] = n * __builtin_amdgcn_rcpf(d + 1e-13f);
    }
}

// ---------------------------------------------------------------------------
extern "C" void kernel_launch(void* const* d_in, const int* in_sizes, int n_in,
                              void* d_out, int out_size, void* d_ws, size_t ws_size,
                              hipStream_t stream) {
    const float* input = (const float*)d_in[0];   // (K, A)    fp32
    const float* abcd  = (const float*)d_in[1];   // (R, A, 4) fp32
    const float* rho   = (const float*)d_in[2];   // (R, A+1)  fp32
    float* out = (float*)d_out;                   // (K,)      fp32

    fuzzy_fused<<<K_TOTAL / KB, 1024, 0, stream>>>(input, abcd, rho, out);
}